// Round 5
// baseline (975.355 us; speedup 1.0000x reference)
//
#include <hip/hip_runtime.h>
#include <hip/hip_bf16.h>
#include <hip/hip_cooperative_groups.h>
#include <cstdint>

namespace cg = cooperative_groups;

#define HW_PIX 262144   // 512*512
#define NSP    16384
#define NE     262144
#define CH     128
#define IMG    512

typedef __attribute__((ext_vector_type(8))) short bf16x8;
typedef __attribute__((ext_vector_type(4))) float f32x4;

__device__ __forceinline__ float b2f(unsigned short u) {
    union { float f; uint32_t i; } v; v.i = ((uint32_t)u) << 16; return v.f;
}
__device__ __forceinline__ unsigned short f2b(float f) {
    union { float f; uint32_t i; } v; v.f = f;
    uint32_t r = (v.i + 0x7FFFu + ((v.i >> 16) & 1u)) >> 16;
    return (unsigned short)r;
}

// ---------------- fused weight prep + count zeroing ----------------
__global__ void prep_all_kernel(const float* __restrict__ W1, const float* __restrict__ b1,
                                const float* __restrict__ W2, const float* __restrict__ b2,
                                const float* __restrict__ Wc, const float* __restrict__ Wl,
                                const float* __restrict__ bc, const float* __restrict__ bl,
                                unsigned short* __restrict__ Bp1, float* __restrict__ bias1,
                                unsigned short* __restrict__ Bp2, float* __restrict__ bias2,
                                unsigned short* __restrict__ BpM, float* __restrict__ bout,
                                int* __restrict__ cpix, int* __restrict__ cedge) {
    int b = blockIdx.x;
    if (b < 256) {
        const float* W  = (b < 128) ? W1 : W2;
        const float* bb = (b < 128) ? b1 : b2;
        unsigned short* Bp = (b < 128) ? Bp1 : Bp2;
        float* bias = (b < 128) ? bias1 : bias2;
        int i = (b & 127) * 256 + threadIdx.x;      // 0..32767
        int j = i & 7, c = (i >> 3) & 15, g = (i >> 7) & 15, t = i >> 11;
        int k = g * 8 + j, n = t * 16 + c;
        float v;
        if (n < 128) v = W[k * 128 + n] - W[(k + 128) * 128 + n];   // Wtop - Wbot
        else         v = W[(k + 128) * 128 + (n - 128)];            // Wbot
        Bp[i] = f2b(v);
        if (i < 256) bias[i] = (i < 128) ? bb[i] : 0.f;
    } else if (b < 328) {
        int i = (b - 256) * 256 + threadIdx.x;      // 9*16*16*8 = 18432
        if (i < 18432) {
            int j = i & 7, c = (i >> 3) & 15, g = (i >> 7) & 15, t = i >> 11;  // t = tap
            int k = g * 8 + j;
            float s = 0.f;
            for (int o = 0; o < 128; ++o)
                s += Wc[(size_t)(o * 128 + k) * 9 + t] * Wl[o * 16 + c];
            BpM[i] = f2b(s);
        }
        if (i < 16) {
            float s = bl[i];
            for (int cc = 0; cc < 128; ++cc) s += bc[cc] * Wl[cc * 16 + i];
            bout[i] = s;
        }
    } else {
        int i = (b - 328) * 256 + threadIdx.x;      // 0..32767
        if (i < NSP) cpix[i] = 0; else cedge[i - NSP] = 0;
    }
}

// ---------------- fused histograms ----------------
__global__ void hist_both_kernel(const int* __restrict__ seg, const int* __restrict__ ei,
                                 int* __restrict__ cpix, int* __restrict__ cedge) {
    int b = blockIdx.x;
    if (b < HW_PIX / 256) {
        int i = b * 256 + threadIdx.x;
        atomicAdd(&cpix[seg[i]], 1);
    } else {
        int e = (b - HW_PIX / 256) * 256 + threadIdx.x;
        atomicAdd(&cedge[ei[NE + e]], 1);   // dst = edge_index[1]
    }
}

// ---------------- exclusive scan of 16384 ints ----------------
__global__ __launch_bounds__(1024) void scan_kernel(const int* __restrict__ cpix, int* __restrict__ opix, int* __restrict__ curpix,
                                                    const int* __restrict__ cedge, int* __restrict__ oedge, int* __restrict__ curedge) {
    const int* cnt = (blockIdx.x == 0) ? cpix : cedge;
    int* offs      = (blockIdx.x == 0) ? opix : oedge;
    int* cur       = (blockIdx.x == 0) ? curpix : curedge;
    __shared__ int tsum[1024];
    int tid = threadIdx.x;
    int loc[16];
    int s = 0;
    #pragma unroll
    for (int q = 0; q < 4; ++q) {
        int4 v = ((const int4*)cnt)[tid * 4 + q];
        loc[q*4+0] = v.x; loc[q*4+1] = v.y; loc[q*4+2] = v.z; loc[q*4+3] = v.w;
    }
    #pragma unroll
    for (int i = 0; i < 16; ++i) { int t = loc[i]; loc[i] = s; s += t; }
    tsum[tid] = s;
    __syncthreads();
    for (int d = 1; d < 1024; d <<= 1) {
        int v = (tid >= d) ? tsum[tid - d] : 0;
        __syncthreads();
        tsum[tid] += v;
        __syncthreads();
    }
    int prefix = tid ? tsum[tid - 1] : 0;
    int base = tid * 16;
    #pragma unroll
    for (int i = 0; i < 16; ++i) { int o = prefix + loc[i]; offs[base + i] = o; cur[base + i] = o; }
    if (tid == 1023) offs[16384] = tsum[1023];
}

// ---------------- fused scatter (counting sort) ----------------
__global__ void scatter_both_kernel(const int* __restrict__ seg, const int* __restrict__ ei,
                                    int* __restrict__ cur_pix, int* __restrict__ cur_edge,
                                    int* __restrict__ sorted_pix, int* __restrict__ sorted_src) {
    int b = blockIdx.x;
    if (b < HW_PIX / 256) {
        int p = b * 256 + threadIdx.x;
        int s = seg[p];
        int pos = atomicAdd(&cur_pix[s], 1);
        sorted_pix[pos] = p;
    } else {
        int e = (b - HW_PIX / 256) * 256 + threadIdx.x;
        int d = ei[NE + e];
        int pos = atomicAdd(&cur_edge[d], 1);
        sorted_src[pos] = ei[e];
    }
}

// ================= fused node pipeline (cooperative) =================

__device__ __forceinline__ void pool_phase(const float* __restrict__ x, const int* __restrict__ offs,
                                           const int* __restrict__ spix, unsigned short* __restrict__ sp) {
    int c = threadIdx.x & 127;
    int half = threadIdx.x >> 7;   // 2 nodes per block-iter
    for (int g = blockIdx.x; g < NSP / 2; g += gridDim.x) {
        int n = g * 2 + half;
        int i0 = offs[n], i1 = offs[n + 1];
        float acc0 = 0.f, acc1 = 0.f, acc2 = 0.f, acc3 = 0.f;
        int i = i0;
        for (; i + 4 <= i1; i += 4) {
            int p0 = spix[i], p1 = spix[i+1], p2 = spix[i+2], p3 = spix[i+3];
            acc0 += x[(size_t)p0 * CH + c];
            acc1 += x[(size_t)p1 * CH + c];
            acc2 += x[(size_t)p2 * CH + c];
            acc3 += x[(size_t)p3 * CH + c];
        }
        for (; i < i1; ++i) acc0 += x[(size_t)spix[i] * CH + c];
        float acc = (acc0 + acc1) + (acc2 + acc3);
        sp[(size_t)n * CH + c] = f2b(acc / fmaxf((float)(i1 - i0), 1.f));
    }
}

__device__ __forceinline__ void gemm_pq_phase(const unsigned short* __restrict__ A,
                                              const unsigned short* __restrict__ Bp,
                                              const float* __restrict__ bias,
                                              unsigned short* __restrict__ C) {
    int tid = threadIdx.x, wid = tid >> 6, lane = tid & 63;
    int lo = lane & 15, kg = lane >> 4;
    for (int wk = blockIdx.x; wk < 1024; wk += gridDim.x) {
        int bx = wk >> 2, gt0 = (wk & 3) * 4;
        int row = bx * 64 + wid * 16 + lo;
        const bf16x8* Arow = (const bf16x8*)(A + (size_t)row * 128);
        f32x4 acc0 = {0,0,0,0}, acc1 = {0,0,0,0}, acc2 = {0,0,0,0}, acc3 = {0,0,0,0};
        #pragma unroll
        for (int s = 0; s < 4; ++s) {
            bf16x8 a = Arow[s * 4 + kg];
            const bf16x8* B0 = (const bf16x8*)Bp + ((gt0 * 16 + s * 4 + kg) * 16 + lo);
            acc0 = __builtin_amdgcn_mfma_f32_16x16x32_bf16(a, B0[0],   acc0, 0, 0, 0);
            acc1 = __builtin_amdgcn_mfma_f32_16x16x32_bf16(a, B0[256], acc1, 0, 0, 0);
            acc2 = __builtin_amdgcn_mfma_f32_16x16x32_bf16(a, B0[512], acc2, 0, 0, 0);
            acc3 = __builtin_amdgcn_mfma_f32_16x16x32_bf16(a, B0[768], acc3, 0, 0, 0);
        }
        int rowbase = bx * 64 + wid * 16 + kg * 4;
        #pragma unroll
        for (int t = 0; t < 4; ++t) {
            f32x4 acc = (t == 0) ? acc0 : (t == 1) ? acc1 : (t == 2) ? acc2 : acc3;
            int gcol = (gt0 + t) * 16 + lo;
            float bv = bias[gcol];
            #pragma unroll
            for (int r = 0; r < 4; ++r)
                C[(size_t)(rowbase + r) * 256 + gcol] = f2b(acc[r] + bv);
        }
    }
}

__device__ __forceinline__ void edge_max_phase(const unsigned short* __restrict__ PQ,
                                               const int* __restrict__ offs,
                                               const int* __restrict__ src,
                                               unsigned short* __restrict__ H) {
    int wid = threadIdx.x >> 6;
    int lane = threadIdx.x & 63;
    int c = lane * 2;
    const unsigned short* Q = PQ + 128 + c;
    for (int n = blockIdx.x * 4 + wid; n < NSP; n += gridDim.x * 4) {
        int i0 = offs[n], i1 = offs[n + 1];
        float m0 = -3.0e38f, m1 = -3.0e38f;
        int i = i0;
        for (; i + 4 <= i1; i += 4) {
            int s0 = src[i], s1 = src[i+1], s2 = src[i+2], s3 = src[i+3];
            uint32_t q0 = *(const uint32_t*)(Q + (size_t)s0 * 256);
            uint32_t q1 = *(const uint32_t*)(Q + (size_t)s1 * 256);
            uint32_t q2 = *(const uint32_t*)(Q + (size_t)s2 * 256);
            uint32_t q3 = *(const uint32_t*)(Q + (size_t)s3 * 256);
            m0 = fmaxf(m0, fmaxf(fmaxf(b2f((unsigned short)(q0 & 0xffff)), b2f((unsigned short)(q1 & 0xffff))),
                                 fmaxf(b2f((unsigned short)(q2 & 0xffff)), b2f((unsigned short)(q3 & 0xffff)))));
            m1 = fmaxf(m1, fmaxf(fmaxf(b2f((unsigned short)(q0 >> 16)), b2f((unsigned short)(q1 >> 16))),
                                 fmaxf(b2f((unsigned short)(q2 >> 16)), b2f((unsigned short)(q3 >> 16)))));
        }
        for (; i < i1; ++i) {
            int s0 = src[i];
            uint32_t q0 = *(const uint32_t*)(Q + (size_t)s0 * 256);
            m0 = fmaxf(m0, b2f((unsigned short)(q0 & 0xffff)));
            m1 = fmaxf(m1, b2f((unsigned short)(q0 >> 16)));
        }
        uint32_t pv = *(const uint32_t*)(PQ + (size_t)n * 256 + c);
        float a0 = fmaxf(0.f, b2f((unsigned short)(pv & 0xffff)) + m0);
        float a1 = fmaxf(0.f, b2f((unsigned short)(pv >> 16)) + m1);
        *(uint32_t*)(H + (size_t)n * 128 + c) = (uint32_t)f2b(a0) | ((uint32_t)f2b(a1) << 16);
    }
}

__device__ __forceinline__ void gemm_tl_phase(const unsigned short* __restrict__ H1,
                                              const unsigned short* __restrict__ H2,
                                              const unsigned short* __restrict__ H3,
                                              const unsigned short* __restrict__ BpM,
                                              float* __restrict__ TL) {
    int tid = threadIdx.x, wid = tid >> 6, lane = tid & 63;
    int lo = lane & 15, kg = lane >> 4;
    for (int wk = blockIdx.x; wk < 768; wk += gridDim.x) {
        int bx = wk & 255, gt0 = (wk >> 8) * 4;   // gt0 in {0,4,8}
        int row = bx * 64 + wid * 16 + lo;
        f32x4 acc0 = {0,0,0,0}, acc1 = {0,0,0,0}, acc2 = {0,0,0,0}, acc3 = {0,0,0,0};
        #pragma unroll
        for (int s = 0; s < 4; ++s) {
            int ci = row * 16 + s * 4 + kg;
            bf16x8 a1 = ((const bf16x8*)H1)[ci];
            bf16x8 a2 = ((const bf16x8*)H2)[ci];
            bf16x8 a3 = ((const bf16x8*)H3)[ci];
            bf16x8 a;
            #pragma unroll
            for (int j = 0; j < 8; ++j)
                a[j] = (short)f2b(b2f((unsigned short)a1[j]) + b2f((unsigned short)a2[j]) + b2f((unsigned short)a3[j]));
            const bf16x8* B0 = (const bf16x8*)BpM + ((gt0 * 16 + s * 4 + kg) * 16 + lo);
            if (gt0 + 0 < 9) acc0 = __builtin_amdgcn_mfma_f32_16x16x32_bf16(a, B0[0],   acc0, 0, 0, 0);
            if (gt0 + 1 < 9) acc1 = __builtin_amdgcn_mfma_f32_16x16x32_bf16(a, B0[256], acc1, 0, 0, 0);
            if (gt0 + 2 < 9) acc2 = __builtin_amdgcn_mfma_f32_16x16x32_bf16(a, B0[512], acc2, 0, 0, 0);
            if (gt0 + 3 < 9) acc3 = __builtin_amdgcn_mfma_f32_16x16x32_bf16(a, B0[768], acc3, 0, 0, 0);
        }
        int rowbase = bx * 64 + wid * 16 + kg * 4;
        #pragma unroll
        for (int t = 0; t < 4; ++t) {
            if (gt0 + t < 9) {
                f32x4 acc = (t == 0) ? acc0 : (t == 1) ? acc1 : (t == 2) ? acc2 : acc3;
                int gcol = (gt0 + t) * 16 + lo;
                #pragma unroll
                for (int r = 0; r < 4; ++r)
                    TL[(size_t)(rowbase + r) * 144 + gcol] = acc[r];
            }
        }
    }
}

__device__ __forceinline__ void conv_phase(const int* __restrict__ seg, const float* __restrict__ TL,
                                           const float* __restrict__ bout, float* __restrict__ out) {
    for (int g = blockIdx.x; g < HW_PIX / 256; g += gridDim.x) {
        int p = g * 256 + threadIdx.x;
        int y = p >> 9, x = p & 511;
        f32x4 a0 = *(const f32x4*)(bout);
        f32x4 a1 = *(const f32x4*)(bout + 4);
        f32x4 a2 = *(const f32x4*)(bout + 8);
        f32x4 a3 = *(const f32x4*)(bout + 12);
        #pragma unroll
        for (int ky = 0; ky < 3; ++ky) {
            int ny = y + ky - 1;
            if ((unsigned)ny >= (unsigned)IMG) continue;
            #pragma unroll
            for (int kx = 0; kx < 3; ++kx) {
                int nx = x + kx - 1;
                if ((unsigned)nx >= (unsigned)IMG) continue;
                const float* t = TL + (size_t)seg[ny * IMG + nx] * 144 + (ky * 3 + kx) * 16;
                a0 += *(const f32x4*)(t);
                a1 += *(const f32x4*)(t + 4);
                a2 += *(const f32x4*)(t + 8);
                a3 += *(const f32x4*)(t + 12);
            }
        }
        float* o = out + (size_t)p * 16;
        *(f32x4*)(o)      = a0;
        *(f32x4*)(o + 4)  = a1;
        *(f32x4*)(o + 8)  = a2;
        *(f32x4*)(o + 12) = a3;
    }
}

__global__ __launch_bounds__(256, 4) void fused_pipeline(
    const float* __restrict__ x,
    const int* __restrict__ offs_pix, const int* __restrict__ sorted_pix,
    const int* __restrict__ offs_edge, const int* __restrict__ sorted_src,
    const unsigned short* __restrict__ Bp1, const float* __restrict__ bias1,
    const unsigned short* __restrict__ Bp2, const float* __restrict__ bias2,
    const unsigned short* __restrict__ BpM, const float* __restrict__ bout,
    const int* __restrict__ seg,
    unsigned short* __restrict__ sp, unsigned short* __restrict__ PQ,
    unsigned short* __restrict__ H1, unsigned short* __restrict__ H2,
    unsigned short* __restrict__ H3, float* __restrict__ TL,
    float* __restrict__ out)
{
    cg::grid_group grid = cg::this_grid();
    pool_phase(x, offs_pix, sorted_pix, sp);
    grid.sync();
    gemm_pq_phase(sp, Bp1, bias1, PQ);
    grid.sync();
    edge_max_phase(PQ, offs_edge, sorted_src, H1);
    grid.sync();
    gemm_pq_phase(H1, Bp2, bias2, PQ);
    grid.sync();
    edge_max_phase(PQ, offs_edge, sorted_src, H2);
    grid.sync();
    gemm_pq_phase(H2, Bp2, bias2, PQ);
    grid.sync();
    edge_max_phase(PQ, offs_edge, sorted_src, H3);
    grid.sync();
    gemm_tl_phase(H1, H2, H3, BpM, TL);
    grid.sync();
    conv_phase(seg, TL, bout, out);
}

extern "C" void kernel_launch(void* const* d_in, const int* in_sizes, int n_in,
                              void* d_out, int out_size, void* d_ws, size_t ws_size,
                              hipStream_t stream) {
    const float* x   = (const float*)d_in[0];
    const int*   ei  = (const int*)d_in[1];
    const int*   seg = (const int*)d_in[2];
    const float* W1  = (const float*)d_in[4];
    const float* b1  = (const float*)d_in[5];
    const float* W2  = (const float*)d_in[6];
    const float* b2  = (const float*)d_in[7];
    const float* Wc  = (const float*)d_in[8];
    const float* bc  = (const float*)d_in[9];
    const float* Wl  = (const float*)d_in[10];
    const float* bl  = (const float*)d_in[11];
    float* out = (float*)d_out;

    char* w = (char*)d_ws;
    auto alloc = [&](size_t bytes) -> void* {
        void* r = (void*)w;
        w += (bytes + 255) & ~(size_t)255;
        return r;
    };
    int* counts_pix  = (int*)alloc(16384 * 4);
    int* offs_pix    = (int*)alloc(16385 * 4);
    int* cur_pix     = (int*)alloc(16384 * 4);
    int* sorted_pix  = (int*)alloc((size_t)HW_PIX * 4);
    int* counts_edge = (int*)alloc(16384 * 4);
    int* offs_edge   = (int*)alloc(16385 * 4);
    int* cur_edge    = (int*)alloc(16384 * 4);
    int* sorted_src  = (int*)alloc((size_t)NE * 4);
    unsigned short* sp  = (unsigned short*)alloc((size_t)NSP * 128 * 2);
    unsigned short* PQ  = (unsigned short*)alloc((size_t)NSP * 256 * 2);
    unsigned short* H1  = (unsigned short*)alloc((size_t)NSP * 128 * 2);
    unsigned short* H2  = (unsigned short*)alloc((size_t)NSP * 128 * 2);
    unsigned short* H3  = (unsigned short*)alloc((size_t)NSP * 128 * 2);
    float* TL = (float*)alloc((size_t)NSP * 144 * 4);
    unsigned short* Bp1 = (unsigned short*)alloc(32768 * 2);
    unsigned short* Bp2 = (unsigned short*)alloc(32768 * 2);
    unsigned short* BpM = (unsigned short*)alloc(18432 * 2);
    float* bias1 = (float*)alloc(256 * 4);
    float* bias2 = (float*)alloc(256 * 4);
    float* boutb = (float*)alloc(16 * 4);

    prep_all_kernel<<<456, 256, 0, stream>>>(W1, b1, W2, b2, Wc, Wl, bc, bl,
                                             Bp1, bias1, Bp2, bias2, BpM, boutb,
                                             counts_pix, counts_edge);
    hist_both_kernel<<<2048, 256, 0, stream>>>(seg, ei, counts_pix, counts_edge);
    scan_kernel<<<2, 1024, 0, stream>>>(counts_pix, offs_pix, cur_pix, counts_edge, offs_edge, cur_edge);
    scatter_both_kernel<<<2048, 256, 0, stream>>>(seg, ei, cur_pix, cur_edge, sorted_pix, sorted_src);

    // cooperative fused pipeline: pool -> 3x(gemm+edge_max) -> gemm_tl -> conv
    int maxBlocksPerCU = 0;
    hipOccupancyMaxActiveBlocksPerMultiprocessor(&maxBlocksPerCU, fused_pipeline, 256, 0);
    if (maxBlocksPerCU < 1) maxBlocksPerCU = 1;
    int grid = maxBlocksPerCU * 256;      // 256 CUs on MI355X
    if (grid > 1024) grid = 1024;

    void* args[] = {
        (void*)&x, (void*)&offs_pix, (void*)&sorted_pix,
        (void*)&offs_edge, (void*)&sorted_src,
        (void*)&Bp1, (void*)&bias1, (void*)&Bp2, (void*)&bias2,
        (void*)&BpM, (void*)&boutb, (void*)&seg,
        (void*)&sp, (void*)&PQ, (void*)&H1, (void*)&H2, (void*)&H3,
        (void*)&TL, (void*)&out
    };
    hipLaunchCooperativeKernel((void*)fused_pipeline, dim3(grid), dim3(256), args, 0, stream);
}

// Round 6
// 203.384 us; speedup vs baseline: 4.7956x; 4.7956x over previous
//
#include <hip/hip_runtime.h>
#include <hip/hip_bf16.h>
#include <cstdint>

#define HW_PIX 262144   // 512*512
#define NSP    16384
#define NE     262144
#define CH     128
#define IMG    512

typedef __attribute__((ext_vector_type(8))) short bf16x8;
typedef __attribute__((ext_vector_type(4))) float f32x4;

__device__ __forceinline__ float b2f(unsigned short u) {
    union { float f; uint32_t i; } v; v.i = ((uint32_t)u) << 16; return v.f;
}
__device__ __forceinline__ unsigned short f2b(float f) {
    union { float f; uint32_t i; } v; v.f = f;
    uint32_t r = (v.i + 0x7FFFu + ((v.i >> 16) & 1u)) >> 16;
    return (unsigned short)r;
}

// ---------------- fused weight prep + count zeroing ----------------
// blocks [0,128): Bp1/bias1, [128,256): Bp2/bias2, [256,328): BpM/bout, [328,456): zero counts
// Bp packing: Bp[((t*16+kg)*16+c)*8+j] = B[kg*8+j][t*16+c]  (MFMA 16x16x32 B-fragment order)
__global__ void prep_all_kernel(const float* __restrict__ W1, const float* __restrict__ b1,
                                const float* __restrict__ W2, const float* __restrict__ b2,
                                const float* __restrict__ Wc, const float* __restrict__ Wl,
                                const float* __restrict__ bc, const float* __restrict__ bl,
                                unsigned short* __restrict__ Bp1, float* __restrict__ bias1,
                                unsigned short* __restrict__ Bp2, float* __restrict__ bias2,
                                unsigned short* __restrict__ BpM, float* __restrict__ bout,
                                int* __restrict__ cpix, int* __restrict__ cedge) {
    int b = blockIdx.x;
    if (b < 256) {
        const float* W  = (b < 128) ? W1 : W2;
        const float* bb = (b < 128) ? b1 : b2;
        unsigned short* Bp = (b < 128) ? Bp1 : Bp2;
        float* bias = (b < 128) ? bias1 : bias2;
        int i = (b & 127) * 256 + threadIdx.x;      // 0..32767
        int j = i & 7, c = (i >> 3) & 15, g = (i >> 7) & 15, t = i >> 11;
        int k = g * 8 + j, n = t * 16 + c;
        float v;
        if (n < 128) v = W[k * 128 + n] - W[(k + 128) * 128 + n];   // Wtop - Wbot
        else         v = W[(k + 128) * 128 + (n - 128)];            // Wbot
        Bp[i] = f2b(v);
        if (i < 256) bias[i] = (i < 128) ? bb[i] : 0.f;
    } else if (b < 328) {
        int i = (b - 256) * 256 + threadIdx.x;      // 9*16*16*8 = 18432
        if (i < 18432) {
            int j = i & 7, c = (i >> 3) & 15, g = (i >> 7) & 15, t = i >> 11;  // t = tap
            int k = g * 8 + j;
            float s = 0.f;
            for (int o = 0; o < 128; ++o)
                s += Wc[(size_t)(o * 128 + k) * 9 + t] * Wl[o * 16 + c];
            BpM[i] = f2b(s);
        }
        if (i < 16) {
            float s = bl[i];
            for (int cc = 0; cc < 128; ++cc) s += bc[cc] * Wl[cc * 16 + i];
            bout[i] = s;
        }
    } else {
        int i = (b - 328) * 256 + threadIdx.x;      // 0..32767
        if (i < NSP) cpix[i] = 0; else cedge[i - NSP] = 0;
    }
}

// ---------------- fused histograms ----------------
__global__ void hist_both_kernel(const int* __restrict__ seg, const int* __restrict__ ei,
                                 int* __restrict__ cpix, int* __restrict__ cedge) {
    int b = blockIdx.x;
    if (b < HW_PIX / 256) {
        int i = b * 256 + threadIdx.x;
        atomicAdd(&cpix[seg[i]], 1);
    } else {
        int e = (b - HW_PIX / 256) * 256 + threadIdx.x;
        atomicAdd(&cedge[ei[NE + e]], 1);   // dst = edge_index[1]
    }
}

// ---------------- exclusive scan of 16384 ints (block 0: pix, block 1: edge) ----------------
__global__ __launch_bounds__(1024) void scan_kernel(const int* __restrict__ cpix, int* __restrict__ opix, int* __restrict__ curpix,
                                                    const int* __restrict__ cedge, int* __restrict__ oedge, int* __restrict__ curedge) {
    const int* cnt = (blockIdx.x == 0) ? cpix : cedge;
    int* offs      = (blockIdx.x == 0) ? opix : oedge;
    int* cur       = (blockIdx.x == 0) ? curpix : curedge;
    __shared__ int tsum[1024];
    int tid = threadIdx.x;
    int loc[16];
    int s = 0;
    #pragma unroll
    for (int q = 0; q < 4; ++q) {
        int4 v = ((const int4*)cnt)[tid * 4 + q];
        loc[q*4+0] = v.x; loc[q*4+1] = v.y; loc[q*4+2] = v.z; loc[q*4+3] = v.w;
    }
    #pragma unroll
    for (int i = 0; i < 16; ++i) { int t = loc[i]; loc[i] = s; s += t; }
    tsum[tid] = s;
    __syncthreads();
    for (int d = 1; d < 1024; d <<= 1) {
        int v = (tid >= d) ? tsum[tid - d] : 0;
        __syncthreads();
        tsum[tid] += v;
        __syncthreads();
    }
    int prefix = tid ? tsum[tid - 1] : 0;
    int base = tid * 16;
    #pragma unroll
    for (int i = 0; i < 16; ++i) { int o = prefix + loc[i]; offs[base + i] = o; cur[base + i] = o; }
    if (tid == 1023) offs[16384] = tsum[1023];
}

// ---------------- fused scatter (counting sort) ----------------
__global__ void scatter_both_kernel(const int* __restrict__ seg, const int* __restrict__ ei,
                                    int* __restrict__ cur_pix, int* __restrict__ cur_edge,
                                    int* __restrict__ sorted_pix, int* __restrict__ sorted_src) {
    int b = blockIdx.x;
    if (b < HW_PIX / 256) {
        int p = b * 256 + threadIdx.x;
        int s = seg[p];
        int pos = atomicAdd(&cur_pix[s], 1);
        sorted_pix[pos] = p;
    } else {
        int e = (b - HW_PIX / 256) * 256 + threadIdx.x;
        int d = ei[NE + e];
        int pos = atomicAdd(&cur_edge[d], 1);
        sorted_src[pos] = ei[e];
    }
}

// ---------------- mean pool pixels -> superpixels (bf16 out), 8-deep pipelined ----------------
__global__ __launch_bounds__(128) void pool_kernel(const float* __restrict__ x, const int* __restrict__ offs,
                                                   const int* __restrict__ spix, unsigned short* __restrict__ sp) {
    int n = blockIdx.x;
    int c = threadIdx.x;
    int i0 = offs[n], i1 = offs[n + 1];
    float a0 = 0.f, a1 = 0.f, a2 = 0.f, a3 = 0.f, a4 = 0.f, a5 = 0.f, a6 = 0.f, a7 = 0.f;
    int i = i0;
    for (; i + 8 <= i1; i += 8) {
        int p0 = spix[i],   p1 = spix[i+1], p2 = spix[i+2], p3 = spix[i+3];
        int p4 = spix[i+4], p5 = spix[i+5], p6 = spix[i+6], p7 = spix[i+7];
        a0 += x[(size_t)p0 * CH + c];
        a1 += x[(size_t)p1 * CH + c];
        a2 += x[(size_t)p2 * CH + c];
        a3 += x[(size_t)p3 * CH + c];
        a4 += x[(size_t)p4 * CH + c];
        a5 += x[(size_t)p5 * CH + c];
        a6 += x[(size_t)p6 * CH + c];
        a7 += x[(size_t)p7 * CH + c];
    }
    for (; i + 4 <= i1; i += 4) {
        int p0 = spix[i], p1 = spix[i+1], p2 = spix[i+2], p3 = spix[i+3];
        a0 += x[(size_t)p0 * CH + c];
        a1 += x[(size_t)p1 * CH + c];
        a2 += x[(size_t)p2 * CH + c];
        a3 += x[(size_t)p3 * CH + c];
    }
    for (; i < i1; ++i) a0 += x[(size_t)spix[i] * CH + c];
    float acc = ((a0 + a1) + (a2 + a3)) + ((a4 + a5) + (a6 + a7));
    sp[(size_t)n * CH + c] = f2b(acc / fmaxf((float)(i1 - i0), 1.f));
}

// ---------------- MFMA bf16 GEMM: PQ[M x 256] = A[M x 128] @ Bp + bias ----------------
__global__ __launch_bounds__(256) void gemm_pq_kernel(const unsigned short* __restrict__ A,
                                                      const unsigned short* __restrict__ Bp,
                                                      const float* __restrict__ bias,
                                                      unsigned short* __restrict__ C) {
    int tid = threadIdx.x, wid = tid >> 6, lane = tid & 63;
    int lo = lane & 15, kg = lane >> 4;
    int row = blockIdx.x * 64 + wid * 16 + lo;
    const bf16x8* Arow = (const bf16x8*)(A + (size_t)row * 128);
    int gt0 = blockIdx.y * 4;
    f32x4 acc0 = {0,0,0,0}, acc1 = {0,0,0,0}, acc2 = {0,0,0,0}, acc3 = {0,0,0,0};
    #pragma unroll
    for (int s = 0; s < 4; ++s) {
        bf16x8 a = Arow[s * 4 + kg];
        const bf16x8* B0 = (const bf16x8*)Bp + ((gt0 * 16 + s * 4 + kg) * 16 + lo);
        acc0 = __builtin_amdgcn_mfma_f32_16x16x32_bf16(a, B0[0],   acc0, 0, 0, 0);
        acc1 = __builtin_amdgcn_mfma_f32_16x16x32_bf16(a, B0[256], acc1, 0, 0, 0);
        acc2 = __builtin_amdgcn_mfma_f32_16x16x32_bf16(a, B0[512], acc2, 0, 0, 0);
        acc3 = __builtin_amdgcn_mfma_f32_16x16x32_bf16(a, B0[768], acc3, 0, 0, 0);
    }
    int rowbase = blockIdx.x * 64 + wid * 16 + kg * 4;
    #pragma unroll
    for (int t = 0; t < 4; ++t) {
        f32x4 acc = (t == 0) ? acc0 : (t == 1) ? acc1 : (t == 2) ? acc2 : acc3;
        int gcol = (gt0 + t) * 16 + lo;
        float bv = bias[gcol];
        #pragma unroll
        for (int r = 0; r < 4; ++r)
            C[(size_t)(rowbase + r) * 256 + gcol] = f2b(acc[r] + bv);
    }
}

// ---------------- MFMA bf16 GEMM with fused H4 = H1+H2+H3: TL[M x 144] f32 ----------------
__global__ __launch_bounds__(256) void gemm_tl_kernel(const unsigned short* __restrict__ H1,
                                                      const unsigned short* __restrict__ H2,
                                                      const unsigned short* __restrict__ H3,
                                                      const unsigned short* __restrict__ BpM,
                                                      float* __restrict__ TL) {
    int tid = threadIdx.x, wid = tid >> 6, lane = tid & 63;
    int lo = lane & 15, kg = lane >> 4;
    int row = blockIdx.x * 64 + wid * 16 + lo;
    int gt0 = blockIdx.y * 4;
    f32x4 acc0 = {0,0,0,0}, acc1 = {0,0,0,0}, acc2 = {0,0,0,0}, acc3 = {0,0,0,0};
    #pragma unroll
    for (int s = 0; s < 4; ++s) {
        int ci = row * 16 + s * 4 + kg;
        bf16x8 a1 = ((const bf16x8*)H1)[ci];
        bf16x8 a2 = ((const bf16x8*)H2)[ci];
        bf16x8 a3 = ((const bf16x8*)H3)[ci];
        bf16x8 a;
        #pragma unroll
        for (int j = 0; j < 8; ++j)
            a[j] = (short)f2b(b2f((unsigned short)a1[j]) + b2f((unsigned short)a2[j]) + b2f((unsigned short)a3[j]));
        const bf16x8* B0 = (const bf16x8*)BpM + ((gt0 * 16 + s * 4 + kg) * 16 + lo);
        if (gt0 + 0 < 9) acc0 = __builtin_amdgcn_mfma_f32_16x16x32_bf16(a, B0[0],   acc0, 0, 0, 0);
        if (gt0 + 1 < 9) acc1 = __builtin_amdgcn_mfma_f32_16x16x32_bf16(a, B0[256], acc1, 0, 0, 0);
        if (gt0 + 2 < 9) acc2 = __builtin_amdgcn_mfma_f32_16x16x32_bf16(a, B0[512], acc2, 0, 0, 0);
        if (gt0 + 3 < 9) acc3 = __builtin_amdgcn_mfma_f32_16x16x32_bf16(a, B0[768], acc3, 0, 0, 0);
    }
    int rowbase = blockIdx.x * 64 + wid * 16 + kg * 4;
    #pragma unroll
    for (int t = 0; t < 4; ++t) {
        if (gt0 + t < 9) {
            f32x4 acc = (t == 0) ? acc0 : (t == 1) ? acc1 : (t == 2) ? acc2 : acc3;
            int gcol = (gt0 + t) * 16 + lo;
            #pragma unroll
            for (int r = 0; r < 4; ++r)
                TL[(size_t)(rowbase + r) * 144 + gcol] = acc[r];
        }
    }
}

// ---------------- per-node edge max, 8-deep pipelined; p hoisted out of loop ----------------
// max_e relu(p + q_e) == max(0, p + max_e q_e)  (addition is monotone; exact in f32)
__global__ __launch_bounds__(256) void edge_max_kernel(const unsigned short* __restrict__ PQ,
                                                       const int* __restrict__ offs,
                                                       const int* __restrict__ src,
                                                       unsigned short* __restrict__ H) {
    int n = blockIdx.x * 4 + (threadIdx.x >> 6);
    int lane = threadIdx.x & 63;
    int c = lane * 2;
    int i0 = offs[n], i1 = offs[n + 1];
    const unsigned short* Q = PQ + 128 + c;
    float m0 = -3.0e38f, m1 = -3.0e38f;
    int i = i0;
    for (; i + 8 <= i1; i += 8) {
        int s0 = src[i],   s1 = src[i+1], s2 = src[i+2], s3 = src[i+3];
        int s4 = src[i+4], s5 = src[i+5], s6 = src[i+6], s7 = src[i+7];
        uint32_t q0 = *(const uint32_t*)(Q + (size_t)s0 * 256);
        uint32_t q1 = *(const uint32_t*)(Q + (size_t)s1 * 256);
        uint32_t q2 = *(const uint32_t*)(Q + (size_t)s2 * 256);
        uint32_t q3 = *(const uint32_t*)(Q + (size_t)s3 * 256);
        uint32_t q4 = *(const uint32_t*)(Q + (size_t)s4 * 256);
        uint32_t q5 = *(const uint32_t*)(Q + (size_t)s5 * 256);
        uint32_t q6 = *(const uint32_t*)(Q + (size_t)s6 * 256);
        uint32_t q7 = *(const uint32_t*)(Q + (size_t)s7 * 256);
        float l0 = fmaxf(fmaxf(b2f((unsigned short)(q0 & 0xffff)), b2f((unsigned short)(q1 & 0xffff))),
                         fmaxf(b2f((unsigned short)(q2 & 0xffff)), b2f((unsigned short)(q3 & 0xffff))));
        float l1 = fmaxf(fmaxf(b2f((unsigned short)(q4 & 0xffff)), b2f((unsigned short)(q5 & 0xffff))),
                         fmaxf(b2f((unsigned short)(q6 & 0xffff)), b2f((unsigned short)(q7 & 0xffff))));
        float h0 = fmaxf(fmaxf(b2f((unsigned short)(q0 >> 16)), b2f((unsigned short)(q1 >> 16))),
                         fmaxf(b2f((unsigned short)(q2 >> 16)), b2f((unsigned short)(q3 >> 16))));
        float h1 = fmaxf(fmaxf(b2f((unsigned short)(q4 >> 16)), b2f((unsigned short)(q5 >> 16))),
                         fmaxf(b2f((unsigned short)(q6 >> 16)), b2f((unsigned short)(q7 >> 16))));
        m0 = fmaxf(m0, fmaxf(l0, l1));
        m1 = fmaxf(m1, fmaxf(h0, h1));
    }
    for (; i + 4 <= i1; i += 4) {
        int s0 = src[i], s1 = src[i+1], s2 = src[i+2], s3 = src[i+3];
        uint32_t q0 = *(const uint32_t*)(Q + (size_t)s0 * 256);
        uint32_t q1 = *(const uint32_t*)(Q + (size_t)s1 * 256);
        uint32_t q2 = *(const uint32_t*)(Q + (size_t)s2 * 256);
        uint32_t q3 = *(const uint32_t*)(Q + (size_t)s3 * 256);
        m0 = fmaxf(m0, fmaxf(fmaxf(b2f((unsigned short)(q0 & 0xffff)), b2f((unsigned short)(q1 & 0xffff))),
                             fmaxf(b2f((unsigned short)(q2 & 0xffff)), b2f((unsigned short)(q3 & 0xffff)))));
        m1 = fmaxf(m1, fmaxf(fmaxf(b2f((unsigned short)(q0 >> 16)), b2f((unsigned short)(q1 >> 16))),
                             fmaxf(b2f((unsigned short)(q2 >> 16)), b2f((unsigned short)(q3 >> 16)))));
    }
    for (; i < i1; ++i) {
        int s0 = src[i];
        uint32_t q0 = *(const uint32_t*)(Q + (size_t)s0 * 256);
        m0 = fmaxf(m0, b2f((unsigned short)(q0 & 0xffff)));
        m1 = fmaxf(m1, b2f((unsigned short)(q0 >> 16)));
    }
    uint32_t pv = *(const uint32_t*)(PQ + (size_t)n * 256 + c);
    // no-edge node: p + (-3e38) stays hugely negative -> fmax(0,.) = 0, matching reference
    float a0 = fmaxf(0.f, b2f((unsigned short)(pv & 0xffff)) + m0);
    float a1 = fmaxf(0.f, b2f((unsigned short)(pv >> 16)) + m1);
    *(uint32_t*)(H + (size_t)n * 128 + c) = (uint32_t)f2b(a0) | ((uint32_t)f2b(a1) << 16);
}

// ---------------- fused conv3x3 + linear: 1 thread/pixel, f32x4 accumulators ----------------
__global__ __launch_bounds__(256) void conv_out_kernel(const int* __restrict__ seg, const float* __restrict__ TL,
                                                       const float* __restrict__ bout, float* __restrict__ out) {
    int p = blockIdx.x * 256 + threadIdx.x;
    int y = p >> 9, x = p & 511;
    f32x4 a0 = *(const f32x4*)(bout);
    f32x4 a1 = *(const f32x4*)(bout + 4);
    f32x4 a2 = *(const f32x4*)(bout + 8);
    f32x4 a3 = *(const f32x4*)(bout + 12);
    #pragma unroll
    for (int ky = 0; ky < 3; ++ky) {
        int ny = y + ky - 1;
        if ((unsigned)ny >= (unsigned)IMG) continue;
        #pragma unroll
        for (int kx = 0; kx < 3; ++kx) {
            int nx = x + kx - 1;
            if ((unsigned)nx >= (unsigned)IMG) continue;
            const float* t = TL + (size_t)seg[ny * IMG + nx] * 144 + (ky * 3 + kx) * 16;
            a0 += *(const f32x4*)(t);
            a1 += *(const f32x4*)(t + 4);
            a2 += *(const f32x4*)(t + 8);
            a3 += *(const f32x4*)(t + 12);
        }
    }
    float* o = out + (size_t)p * 16;
    *(f32x4*)(o)      = a0;
    *(f32x4*)(o + 4)  = a1;
    *(f32x4*)(o + 8)  = a2;
    *(f32x4*)(o + 12) = a3;
}

extern "C" void kernel_launch(void* const* d_in, const int* in_sizes, int n_in,
                              void* d_out, int out_size, void* d_ws, size_t ws_size,
                              hipStream_t stream) {
    const float* x   = (const float*)d_in[0];
    const int*   ei  = (const int*)d_in[1];
    const int*   seg = (const int*)d_in[2];
    const float* W1  = (const float*)d_in[4];
    const float* b1  = (const float*)d_in[5];
    const float* W2  = (const float*)d_in[6];
    const float* b2  = (const float*)d_in[7];
    const float* Wc  = (const float*)d_in[8];
    const float* bc  = (const float*)d_in[9];
    const float* Wl  = (const float*)d_in[10];
    const float* bl  = (const float*)d_in[11];
    float* out = (float*)d_out;

    char* w = (char*)d_ws;
    auto alloc = [&](size_t bytes) -> void* {
        void* r = (void*)w;
        w += (bytes + 255) & ~(size_t)255;
        return r;
    };
    int* counts_pix  = (int*)alloc(16384 * 4);
    int* offs_pix    = (int*)alloc(16385 * 4);
    int* cur_pix     = (int*)alloc(16384 * 4);
    int* sorted_pix  = (int*)alloc((size_t)HW_PIX * 4);
    int* counts_edge = (int*)alloc(16384 * 4);
    int* offs_edge   = (int*)alloc(16385 * 4);
    int* cur_edge    = (int*)alloc(16384 * 4);
    int* sorted_src  = (int*)alloc((size_t)NE * 4);
    unsigned short* sp  = (unsigned short*)alloc((size_t)NSP * 128 * 2);
    unsigned short* PQ  = (unsigned short*)alloc((size_t)NSP * 256 * 2);
    unsigned short* H1  = (unsigned short*)alloc((size_t)NSP * 128 * 2);
    unsigned short* H2  = (unsigned short*)alloc((size_t)NSP * 128 * 2);
    unsigned short* H3  = (unsigned short*)alloc((size_t)NSP * 128 * 2);
    float* TL = (float*)alloc((size_t)NSP * 144 * 4);
    unsigned short* Bp1 = (unsigned short*)alloc(32768 * 2);
    unsigned short* Bp2 = (unsigned short*)alloc(32768 * 2);
    unsigned short* BpM = (unsigned short*)alloc(18432 * 2);
    float* bias1 = (float*)alloc(256 * 4);
    float* bias2 = (float*)alloc(256 * 4);
    float* boutb = (float*)alloc(16 * 4);

    prep_all_kernel<<<456, 256, 0, stream>>>(W1, b1, W2, b2, Wc, Wl, bc, bl,
                                             Bp1, bias1, Bp2, bias2, BpM, boutb,
                                             counts_pix, counts_edge);
    hist_both_kernel<<<2048, 256, 0, stream>>>(seg, ei, counts_pix, counts_edge);
    scan_kernel<<<2, 1024, 0, stream>>>(counts_pix, offs_pix, cur_pix, counts_edge, offs_edge, cur_edge);
    scatter_both_kernel<<<2048, 256, 0, stream>>>(seg, ei, cur_pix, cur_edge, sorted_pix, sorted_src);

    pool_kernel<<<NSP, 128, 0, stream>>>(x, offs_pix, sorted_pix, sp);

    dim3 gPQ(NSP / 64, 4);
    dim3 gTL(NSP / 64, 3);

    gemm_pq_kernel<<<gPQ, 256, 0, stream>>>(sp, Bp1, bias1, PQ);
    edge_max_kernel<<<NSP / 4, 256, 0, stream>>>(PQ, offs_edge, sorted_src, H1);
    gemm_pq_kernel<<<gPQ, 256, 0, stream>>>(H1, Bp2, bias2, PQ);
    edge_max_kernel<<<NSP / 4, 256, 0, stream>>>(PQ, offs_edge, sorted_src, H2);
    gemm_pq_kernel<<<gPQ, 256, 0, stream>>>(H2, Bp2, bias2, PQ);
    edge_max_kernel<<<NSP / 4, 256, 0, stream>>>(PQ, offs_edge, sorted_src, H3);

    gemm_tl_kernel<<<gTL, 256, 0, stream>>>(H1, H2, H3, BpM, TL);

    conv_out_kernel<<<HW_PIX / 256, 256, 0, stream>>>(seg, TL, boutb, out);
}